// Round 21
// baseline (225.683 us; speedup 1.0000x reference)
//
#include <hip/hip_runtime.h>
#include <hip/hip_bf16.h>
#include <stdint.h>

#define DM 768
#define DK 64
#define NH 12
#define SQ 4096
#define BB 2

typedef __attribute__((ext_vector_type(8))) short bf16x8;
typedef __attribute__((ext_vector_type(4))) float f32x4;
typedef __attribute__((ext_vector_type(16))) float f32x16;
typedef __attribute__((ext_vector_type(4))) unsigned short u16x4;
typedef __attribute__((ext_vector_type(4))) unsigned int u32x4;
typedef unsigned short u16;
typedef unsigned int   u32;

__device__ __forceinline__ u16 f2bf(float f) {
    u32 u = __builtin_bit_cast(u32, f);
    u32 r = (u + 0x7fffu + ((u >> 16) & 1u)) >> 16;   // RNE
    return (u16)r;
}
// pack two positive f32 -> (bf16,bf16) via byte-select truncation (verified r6)
__device__ __forceinline__ u32 pack_trunc(float lo, float hi) {
    return __builtin_amdgcn_perm(__builtin_bit_cast(u32, hi),
                                 __builtin_bit_cast(u32, lo), 0x07060302u);
}
// async global->LDS, 16B per lane; LDS dest = wave-uniform base + lane*16
__device__ __forceinline__ void gl_lds16(const u16* g, u16* l) {
    __builtin_amdgcn_global_load_lds(
        (const __attribute__((address_space(1))) void*)g,
        (__attribute__((address_space(3))) void*)l, 16, 0, 0);
}

// ---------------------------------------------------------------------------
// f32 -> bf16 conversion for the four weight matrices (verified r12)
// ---------------------------------------------------------------------------
__global__ __launch_bounds__(256) void cvt_w(
    const float* __restrict__ W0, const float* __restrict__ W1,
    const float* __restrict__ W2, const float* __restrict__ W3,
    u16* __restrict__ d0, u16* __restrict__ d1,
    u16* __restrict__ d2, u16* __restrict__ d3)
{
    const float* s = blockIdx.y == 0 ? W0 : blockIdx.y == 1 ? W1
                   : blockIdx.y == 2 ? W2 : W3;
    u16* d        = blockIdx.y == 0 ? d0 : blockIdx.y == 1 ? d1
                   : blockIdx.y == 2 ? d2 : d3;
    size_t i = ((size_t)blockIdx.x * 256 + threadIdx.x) * 8;
    float4 a = *(const float4*)&s[i];
    float4 b = *(const float4*)&s[i + 4];
    u16x4 lo, hi;
    lo.x = f2bf(a.x); lo.y = f2bf(a.y); lo.z = f2bf(a.z); lo.w = f2bf(a.w);
    hi.x = f2bf(b.x); hi.y = f2bf(b.y); hi.z = f2bf(b.z); hi.w = f2bf(b.w);
    *(u16x4*)&d[i]     = lo;
    *(u16x4*)&d[i + 4] = hi;
}

// ---------------------------------------------------------------------------
// Fused QKV projection GEMM (verified r16): f32 A converted in staging;
// W bf16 via DMA; 2-phase double buffer; V^T stored with kv bits 2<->3
// swapped (sigma) so flash PV needs no cross-half exchange.
// ---------------------------------------------------------------------------
#define BM 128
#define BN 128

__global__ __launch_bounds__(256) void gemm_qkv(
    const float* __restrict__ A0, const float* __restrict__ A1,
    const float* __restrict__ A2,
    const u16* __restrict__ W0, const u16* __restrict__ W1,
    const u16* __restrict__ W2,
    const float* __restrict__ b0, const float* __restrict__ b1,
    const float* __restrict__ b2,
    u16* __restrict__ qo, u16* __restrict__ ko, u16* __restrict__ vto,
    float qscale)
{
    __shared__ __align__(16) u16 Asm[2][BM * 32];
    __shared__ __align__(16) u16 Bsm[2][BM * 32];

    const int tid  = threadIdx.x;
    const int lane = tid & 63;
    const int w    = tid >> 6;
    const int wr   = w >> 1, wc = w & 1;
    const int l16  = lane & 15, lg = lane >> 4;

    const int ntiles = DM / BN;                 // 6
    const int mt = blockIdx.x / ntiles;
    const int nt = blockIdx.x % ntiles;
    const int m0 = mt * BM, n0 = nt * BN;

    const int op = blockIdx.y;                  // 0=Q 1=K 2=V
    const float* A    = op == 0 ? A0 : op == 1 ? A1 : A2;
    const u16*  W     = op == 0 ? W0 : op == 1 ? W1 : W2;
    const float* bias = op == 0 ? b0 : op == 1 ? b1 : b2;
    const float oscale = op == 0 ? qscale : 1.0f;

    f32x4 acc[4][4];
    #pragma unroll
    for (int mi = 0; mi < 4; ++mi)
        #pragma unroll
        for (int ni = 0; ni < 4; ++ni)
            #pragma unroll
            for (int r = 0; r < 4; ++r) acc[mi][ni][r] = 0.f;

    #define GSTAGE(K0, B)                                                      \
        do {                                                                   \
            _Pragma("unroll")                                                  \
            for (int i_ = 0; i_ < 2; ++i_) {                                   \
                int c_   = (i_ * 4 + w) * 64 + lane;                           \
                int row_ = c_ >> 2;                                            \
                int col_ = ((c_ & 3) ^ (row_ & 3)) * 8;                        \
                gl_lds16(&W[(size_t)(n0 + row_) * DM + (K0) + col_],           \
                         &Bsm[B][(i_ * 4 + w) * 512]);                         \
            }                                                                  \
            _Pragma("unroll")                                                  \
            for (int i_ = 0; i_ < 2; ++i_) {                                   \
                int s_   = tid + i_ * 256;                                     \
                int row_ = s_ >> 2;                                            \
                int col_ = ((s_ & 3) ^ (row_ & 3)) * 8;                        \
                float4 x_ = *(const float4*)&A[(size_t)(m0 + row_) * DM + (K0) + col_];     \
                float4 y_ = *(const float4*)&A[(size_t)(m0 + row_) * DM + (K0) + col_ + 4]; \
                u16x4 lo_, hi_;                                                \
                lo_.x = f2bf(x_.x); lo_.y = f2bf(x_.y);                        \
                lo_.z = f2bf(x_.z); lo_.w = f2bf(x_.w);                        \
                hi_.x = f2bf(y_.x); hi_.y = f2bf(y_.y);                        \
                hi_.z = f2bf(y_.z); hi_.w = f2bf(y_.w);                        \
                *(u16x4*)&Asm[B][s_ * 8]     = lo_;                            \
                *(u16x4*)&Asm[B][s_ * 8 + 4] = hi_;                            \
            }                                                                  \
        } while (0)

    GSTAGE(0, 0);

    for (int kk = 0; kk < DM / 32; ++kk) {
        __syncthreads();                       // publishes buf[kk&1]
        if (kk + 1 < DM / 32) GSTAGE((kk + 1) * 32, (kk + 1) & 1);

        const u16* Ab = Asm[kk & 1];
        const u16* Bb = Bsm[kk & 1];
        bf16x8 af[4], bfr[4];
        #pragma unroll
        for (int mi = 0; mi < 4; ++mi) {
            int r = wr * 64 + mi * 16 + l16;
            af[mi] = *(const bf16x8*)((const char*)Ab + (size_t)r * 64
                                      + (((lg ^ r) & 3) << 4));
        }
        #pragma unroll
        for (int ni = 0; ni < 4; ++ni) {
            int r = wc * 64 + ni * 16 + l16;
            bfr[ni] = *(const bf16x8*)((const char*)Bb + (size_t)r * 64
                                       + (((lg ^ r) & 3) << 4));
        }

        #pragma unroll
        for (int mi = 0; mi < 4; ++mi)
            #pragma unroll
            for (int ni = 0; ni < 4; ++ni)
                acc[mi][ni] = __builtin_amdgcn_mfma_f32_16x16x32_bf16(
                    af[mi], bfr[ni], acc[mi][ni], 0, 0, 0);
    }
    #undef GSTAGE

    #pragma unroll
    for (int mi = 0; mi < 4; ++mi)
        #pragma unroll
        for (int ni = 0; ni < 4; ++ni) {
            int n = n0 + wc * 64 + ni * 16 + l16;
            float bv = bias[n];
            if (op == 2) {
                int hh = n >> 6, dd = n & 63;
                int mb = m0 + wr * 64 + mi * 16 + lg * 4;
                int bI = mb >> 12;
                int kv = mb & (SQ - 1);
                int kvs = (kv & ~12) | ((kv & 4) << 1) | ((kv & 8) >> 1);
                u16x4 pk;
                #pragma unroll
                for (int r = 0; r < 4; ++r)
                    pk[r] = f2bf(acc[mi][ni][r] + bv);
                *(u16x4*)&vto[(((size_t)bI * NH + hh) * DK + dd) * SQ + kvs] = pk;
            } else {
                u16* out = op ? ko : qo;
                #pragma unroll
                for (int r = 0; r < 4; ++r) {
                    int m = m0 + wr * 64 + mi * 16 + lg * 4 + r;
                    out[(size_t)m * DM + n] = f2bf((acc[mi][ni][r] + bv) * oscale);
                }
            }
        }
}

// ---------------------------------------------------------------------------
// Final projection GEMM, 64x128 tile, 768 blocks (verified r16).
// ---------------------------------------------------------------------------
__global__ __launch_bounds__(256) void gemm_out(
    const u16* __restrict__ A, const u16* __restrict__ W,
    const float* __restrict__ bias, float* __restrict__ C)
{
    __shared__ __align__(16) u16 Asm[2][64 * 32];
    __shared__ __align__(16) u16 Bsm[2][128 * 32];

    const int tid  = threadIdx.x;
    const int lane = tid & 63;
    const int w    = tid >> 6;
    const int wr   = w >> 1, wc = w & 1;
    const int l16  = lane & 15, lg = lane >> 4;

    const int ntiles = DM / 128;                // 6
    const int mt = blockIdx.x / ntiles;
    const int nt = blockIdx.x % ntiles;
    const int m0 = mt * 64, n0 = nt * 128;

    f32x4 acc[2][4];
    #pragma unroll
    for (int mi = 0; mi < 2; ++mi)
        #pragma unroll
        for (int ni = 0; ni < 4; ++ni)
            #pragma unroll
            for (int r = 0; r < 4; ++r) acc[mi][ni][r] = 0.f;

    #define OSTAGE(K0, B)                                                      \
        do {                                                                   \
            _Pragma("unroll")                                                  \
            for (int i_ = 0; i_ < 2; ++i_) {                                   \
                int c_   = (i_ * 4 + w) * 64 + lane;                           \
                int row_ = c_ >> 2;                                            \
                int col_ = ((c_ & 3) ^ (row_ & 3)) * 8;                        \
                gl_lds16(&W[(size_t)(n0 + row_) * DM + (K0) + col_],           \
                         &Bsm[B][(i_ * 4 + w) * 512]);                         \
            }                                                                  \
            {                                                                  \
                int c_   = w * 64 + lane;                                      \
                int row_ = c_ >> 2;                                            \
                int col_ = ((c_ & 3) ^ (row_ & 3)) * 8;                        \
                gl_lds16(&A[(size_t)(m0 + row_) * DM + (K0) + col_],           \
                         &Asm[B][w * 512]);                                    \
            }                                                                  \
        } while (0)

    OSTAGE(0, 0);

    for (int kk = 0; kk < DM / 32; ++kk) {
        __syncthreads();
        if (kk + 1 < DM / 32) OSTAGE((kk + 1) * 32, (kk + 1) & 1);

        const u16* Ab = Asm[kk & 1];
        const u16* Bb = Bsm[kk & 1];
        bf16x8 af[2], bfr[4];
        #pragma unroll
        for (int mi = 0; mi < 2; ++mi) {
            int r = wr * 32 + mi * 16 + l16;
            af[mi] = *(const bf16x8*)((const char*)Ab + (size_t)r * 64
                                      + (((lg ^ r) & 3) << 4));
        }
        #pragma unroll
        for (int ni = 0; ni < 4; ++ni) {
            int r = wc * 64 + ni * 16 + l16;
            bfr[ni] = *(const bf16x8*)((const char*)Bb + (size_t)r * 64
                                       + (((lg ^ r) & 3) << 4));
        }

        #pragma unroll
        for (int mi = 0; mi < 2; ++mi)
            #pragma unroll
            for (int ni = 0; ni < 4; ++ni)
                acc[mi][ni] = __builtin_amdgcn_mfma_f32_16x16x32_bf16(
                    af[mi], bfr[ni], acc[mi][ni], 0, 0, 0);
    }
    #undef OSTAGE

    #pragma unroll
    for (int mi = 0; mi < 2; ++mi)
        #pragma unroll
        for (int ni = 0; ni < 4; ++ni) {
            int n = n0 + wc * 64 + ni * 16 + l16;
            float bv = bias[n];
            #pragma unroll
            for (int r = 0; r < 4; ++r) {
                int m = m0 + wr * 32 + mi * 16 + lg * 4 + r;
                C[(size_t)m * DM + n] = acc[mi][ni][r] + bv;
            }
        }
}

// ---------------------------------------------------------------------------
// Flash attention v12: r16 structure with KVBLK=64 (32 kv per half) so
// LDS = 2x16KB buffers + 35KB merge overlay = 36KB -> 3 blocks co-resident
// (24 waves/CU, no serial tail generation). K path identical math; V^T
// tile is [64 d][32 kv] (64B rows, 4-chunk involution swizzle). sigma,
// p=2^s, XCD swizzle, merge: verified r16 pieces.
// ---------------------------------------------------------------------------
__global__ __launch_bounds__(512) void flash_attn_v12(
    const u16* __restrict__ Qm, const u16* __restrict__ Km,
    const u16* __restrict__ VT, u16* __restrict__ Om)
{
    // union: 2 buffers x (2 halves x (K 4KB | V 4KB)) = 32KB  /  merge 35.3KB
    __shared__ __align__(16) char ldsbuf[36864];

    const int tid  = threadIdx.x;
    const int lane = tid & 63;
    const int w    = tid >> 6;          // 0..7
    const int qg   = w & 3;
    const int half = w >> 2;
    const int kvL  = lane & 31;
    const int hi   = lane >> 5;

    const int bid = blockIdx.x;                  // 0..767
    const int grp = bid >> 3;                    // 0..95
    const int bh  = (bid & 7) * 3 + (grp >> 5);  // 0..23 (bijective)
    const int qt  = grp & 31;                    // 0..31
    const int b   = bh / NH, h = bh % NH;
    const size_t baseQ  = (size_t)b * SQ * DM + (size_t)h * DK;
    const size_t baseVT = (size_t)bh * DK * SQ;

    const int q = qt * 128 + qg * 32 + kvL;

    bf16x8 qf[4];
    #pragma unroll
    for (int j = 0; j < 4; ++j)
        qf[j] = *(const bf16x8*)&Qm[baseQ + (size_t)q * DM + j * 16 + hi * 8];

    // K fragment offsets (128B rows, verified swizzle)
    int off[4];
    #pragma unroll
    for (int j = 0; j < 4; ++j)
        off[j] = kvL * 128 + (((2 * j + hi) ^ (kvL & 7)) << 4);
    // V fragment offsets (64B rows, 4-chunk swizzle); +2048 for d=32..63
    int voff[2];
    #pragma unroll
    for (int m = 0; m < 2; ++m)
        voff[m] = kvL * 64 + (((2 * m + hi) ^ (kvL & 3)) << 4);

    // staging decode: per half, K tile [32 kv][128B] (wave issues rows
    // qg*8+..), V tile [64 d][64B] (wave issues rows qg*16+..); source
    // chunks pre-swizzled (involution) so linear DMA lands swizzled.
    const int krow = qg * 8 + (lane >> 3);
    const int kchk = (((lane & 7) ^ (krow & 7)) << 3);
    const int vrow = qg * 16 + (lane >> 2);
    const int vchk = (((lane & 3) ^ (vrow & 3)) << 3);

    f32x16 accO[2];
    #pragma unroll
    for (int e = 0; e < 16; ++e) { accO[0][e] = 0.f; accO[1][e] = 0.f; }
    float lrun = 0.f;

    #define STAGE(T, B)                                                        \
        do {                                                                   \
            int kv0_ = (T) * 64 + half * 32;                                   \
            u16* KL_ = (u16*)(ldsbuf + (B) * 16384 + half * 8192);             \
            u16* VL_ = (u16*)(ldsbuf + (B) * 16384 + half * 8192 + 4096);      \
            gl_lds16(&Km[baseQ + (size_t)(kv0_ + krow) * DM + kchk],           \
                     KL_ + qg * 512);                                          \
            gl_lds16(&VT[baseVT + (size_t)vrow * SQ + kv0_ + vchk],            \
                     VL_ + qg * 512);                                          \
        } while (0)

    STAGE(0, 0);

    for (int t = 0; t < SQ / 64; ++t) {
        __syncthreads();                // drains own DMA; publishes buf[t&1]
        if (t + 1 < SQ / 64) STAGE(t + 1, (t + 1) & 1);

        const char* KB = ldsbuf + (t & 1) * 16384 + half * 8192;
        const char* VB = KB + 4096;

        // S^T = K . Q (log2 domain): one 32x32 tile (32 kv rows)
        f32x16 s0;
        #pragma unroll
        for (int e = 0; e < 16; ++e) s0[e] = 0.f;
        __builtin_amdgcn_s_setprio(1);
        #pragma unroll
        for (int j = 0; j < 4; ++j) {
            bf16x8 kf = *(const bf16x8*)(KB + off[j]);
            s0 = __builtin_amdgcn_mfma_f32_32x32x16_bf16(kf, qf[j], s0, 0, 0, 0);
        }
        __builtin_amdgcn_s_setprio(0);

        // p = 2^s; per-lane partial row sum
        u32 pb[8];
        float rs = 0.f;
        #pragma unroll
        for (int wd = 0; wd < 8; ++wd) {
            float a0 = __builtin_amdgcn_exp2f(s0[2 * wd]);
            float a1 = __builtin_amdgcn_exp2f(s0[2 * wd + 1]);
            rs += a0 + a1;
            pb[wd] = pack_trunc(a0, a1);
        }
        lrun += rs;

        // PV: lane's own pb words ARE the B-fragment (sigma V^T)
        __builtin_amdgcn_s_setprio(1);
        #pragma unroll
        for (int m = 0; m < 2; ++m) {
            u32x4 wds;
            wds[0] = pb[4 * m + 0];
            wds[1] = pb[4 * m + 1];
            wds[2] = pb[4 * m + 2];
            wds[3] = pb[4 * m + 3];
            bf16x8 Bp = __builtin_bit_cast(bf16x8, wds);
            bf16x8 v0 = *(const bf16x8*)(VB + voff[m]);
            bf16x8 v1 = *(const bf16x8*)(VB + 2048 + voff[m]);
            accO[0] = __builtin_amdgcn_mfma_f32_32x32x16_bf16(v0, Bp, accO[0], 0, 0, 0);
            accO[1] = __builtin_amdgcn_mfma_f32_32x32x16_bf16(v1, Bp, accO[1], 0, 0, 0);
        }
        __builtin_amdgcn_s_setprio(0);
    }
    #undef STAGE

    __syncthreads();                    // all compute done before merge overlay

    lrun = lrun + __shfl_xor(lrun, 32);

    // ---- cross-wave (kv-split) merge (verified r16) ----
    float* mo = (float*)ldsbuf;                    // [qg][q=32][68] f32
    float* ml = (float*)(ldsbuf + 34816);          // [qg*32+q] f32
    const int rowi = (qg * 32 + kvL);

    if (half == 1) {
        float* row = mo + rowi * 68;
        #pragma unroll
        for (int c = 0; c < 2; ++c)
            #pragma unroll
            for (int e = 0; e < 16; ++e)
                row[(e >> 2) * 8 + (e & 3) + hi * 4 + c * 32] = accO[c][e];
        if (hi == 0) ml[rowi] = lrun;
    }
    __syncthreads();
    if (half == 0) {
        float* row = mo + rowi * 68;
        float inv = 1.f / (lrun + ml[rowi]);
        #pragma unroll
        for (int c = 0; c < 2; ++c)
            #pragma unroll
            for (int t4 = 0; t4 < 4; ++t4) {
                int d0 = t4 * 8 + hi * 4 + c * 32;
                u16x4 pk;
                #pragma unroll
                for (int u = 0; u < 4; ++u) {
                    float val = (accO[c][t4 * 4 + u] + row[d0 + u]) * inv;
                    pk[u] = f2bf(val);
                }
                *(u16x4*)&Om[baseQ + (size_t)q * DM + d0] = pk;
            }
    }
}

// ---------------------------------------------------------------------------
extern "C" void kernel_launch(void* const* d_in, const int* in_sizes, int n_in,
                              void* d_out, int out_size, void* d_ws, size_t ws_size,
                              hipStream_t stream)
{
    const float* Q  = (const float*)d_in[0];
    const float* K  = (const float*)d_in[1];
    const float* V  = (const float*)d_in[2];
    const float* Wq = (const float*)d_in[3];
    const float* bq = (const float*)d_in[4];
    const float* Wk = (const float*)d_in[5];
    const float* bk = (const float*)d_in[6];
    const float* Wv = (const float*)d_in[7];
    const float* bv = (const float*)d_in[8];
    const float* Wo = (const float*)d_in[9];
    const float* bo = (const float*)d_in[10];
    (void)in_sizes; (void)n_in; (void)out_size; (void)ws_size;

    const size_t E  = (size_t)BB * SQ * DM;      // 6291456
    const size_t WE = (size_t)DM * DM;           // 589824
    u16* qws  = (u16*)d_ws;
    u16* kws  = qws + E;
    u16* vtws = kws + E;
    u16* aws  = vtws + E;
    u16* wqb  = aws + E;
    u16* wkb  = wqb + WE;
    u16* wvb  = wkb + WE;
    u16* wob  = wvb + WE;

    const float qscale = 0.125f * 1.4426950408889634f;   // 1/sqrt(64) * log2(e)

    hipLaunchKernelGGL(cvt_w, dim3(WE / 2048, 4), dim3(256), 0, stream,
                       Wq, Wk, Wv, Wo, wqb, wkb, wvb, wob);

    dim3 gq((BB * SQ / BM) * (DM / BN), 3);      // (384, 3)
    hipLaunchKernelGGL(gemm_qkv, gq, dim3(256), 0, stream,
                       Q, K, V, wqb, wkb, wvb, bq, bk, bv,
                       qws, kws, vtws, qscale);

    dim3 ga(768);                                // swizzled 1D grid
    hipLaunchKernelGGL(flash_attn_v12, ga, dim3(512), 0, stream, qws, kws, vtws, aws);

    dim3 gg((BB * SQ / 64) * (DM / 128));        // 128*6 = 768
    hipLaunchKernelGGL(gemm_out, gg, dim3(256), 0, stream, aws, wob, bo, (float*)d_out);
}

// Round 22
// 220.284 us; speedup vs baseline: 1.0245x; 1.0245x over previous
//
#include <hip/hip_runtime.h>
#include <hip/hip_bf16.h>
#include <stdint.h>

#define DM 768
#define DK 64
#define NH 12
#define SQ 4096
#define BB 2

typedef __attribute__((ext_vector_type(8))) short bf16x8;
typedef __attribute__((ext_vector_type(4))) float f32x4;
typedef __attribute__((ext_vector_type(16))) float f32x16;
typedef __attribute__((ext_vector_type(4))) unsigned short u16x4;
typedef __attribute__((ext_vector_type(4))) unsigned int u32x4;
typedef unsigned short u16;
typedef unsigned int   u32;

__device__ __forceinline__ u16 f2bf(float f) {
    u32 u = __builtin_bit_cast(u32, f);
    u32 r = (u + 0x7fffu + ((u >> 16) & 1u)) >> 16;   // RNE
    return (u16)r;
}
// pack two positive f32 -> (bf16,bf16) via byte-select truncation (verified r6)
__device__ __forceinline__ u32 pack_trunc(float lo, float hi) {
    return __builtin_amdgcn_perm(__builtin_bit_cast(u32, hi),
                                 __builtin_bit_cast(u32, lo), 0x07060302u);
}
// async global->LDS, 16B per lane; LDS dest = wave-uniform base + lane*16
__device__ __forceinline__ void gl_lds16(const u16* g, u16* l) {
    __builtin_amdgcn_global_load_lds(
        (const __attribute__((address_space(1))) void*)g,
        (__attribute__((address_space(3))) void*)l, 16, 0, 0);
}

// ---------------------------------------------------------------------------
// f32 -> bf16 conversion for the four weight matrices (verified r12)
// ---------------------------------------------------------------------------
__global__ __launch_bounds__(256) void cvt_w(
    const float* __restrict__ W0, const float* __restrict__ W1,
    const float* __restrict__ W2, const float* __restrict__ W3,
    u16* __restrict__ d0, u16* __restrict__ d1,
    u16* __restrict__ d2, u16* __restrict__ d3)
{
    const float* s = blockIdx.y == 0 ? W0 : blockIdx.y == 1 ? W1
                   : blockIdx.y == 2 ? W2 : W3;
    u16* d        = blockIdx.y == 0 ? d0 : blockIdx.y == 1 ? d1
                   : blockIdx.y == 2 ? d2 : d3;
    size_t i = ((size_t)blockIdx.x * 256 + threadIdx.x) * 8;
    float4 a = *(const float4*)&s[i];
    float4 b = *(const float4*)&s[i + 4];
    u16x4 lo, hi;
    lo.x = f2bf(a.x); lo.y = f2bf(a.y); lo.z = f2bf(a.z); lo.w = f2bf(a.w);
    hi.x = f2bf(b.x); hi.y = f2bf(b.y); hi.z = f2bf(b.z); hi.w = f2bf(b.w);
    *(u16x4*)&d[i]     = lo;
    *(u16x4*)&d[i + 4] = hi;
}

// ---------------------------------------------------------------------------
// Fused QKV projection GEMM (verified r16): f32 A converted in staging;
// W bf16 via DMA; 2-phase double buffer; V^T stored with kv bits 2<->3
// swapped (sigma) so flash PV needs no cross-half exchange.
// ---------------------------------------------------------------------------
#define BM 128
#define BN 128

__global__ __launch_bounds__(256) void gemm_qkv(
    const float* __restrict__ A0, const float* __restrict__ A1,
    const float* __restrict__ A2,
    const u16* __restrict__ W0, const u16* __restrict__ W1,
    const u16* __restrict__ W2,
    const float* __restrict__ b0, const float* __restrict__ b1,
    const float* __restrict__ b2,
    u16* __restrict__ qo, u16* __restrict__ ko, u16* __restrict__ vto,
    float qscale)
{
    __shared__ __align__(16) u16 Asm[2][BM * 32];
    __shared__ __align__(16) u16 Bsm[2][BM * 32];

    const int tid  = threadIdx.x;
    const int lane = tid & 63;
    const int w    = tid >> 6;
    const int wr   = w >> 1, wc = w & 1;
    const int l16  = lane & 15, lg = lane >> 4;

    const int ntiles = DM / BN;                 // 6
    const int mt = blockIdx.x / ntiles;
    const int nt = blockIdx.x % ntiles;
    const int m0 = mt * BM, n0 = nt * BN;

    const int op = blockIdx.y;                  // 0=Q 1=K 2=V
    const float* A    = op == 0 ? A0 : op == 1 ? A1 : A2;
    const u16*  W     = op == 0 ? W0 : op == 1 ? W1 : W2;
    const float* bias = op == 0 ? b0 : op == 1 ? b1 : b2;
    const float oscale = op == 0 ? qscale : 1.0f;

    f32x4 acc[4][4];
    #pragma unroll
    for (int mi = 0; mi < 4; ++mi)
        #pragma unroll
        for (int ni = 0; ni < 4; ++ni)
            #pragma unroll
            for (int r = 0; r < 4; ++r) acc[mi][ni][r] = 0.f;

    #define GSTAGE(K0, B)                                                      \
        do {                                                                   \
            _Pragma("unroll")                                                  \
            for (int i_ = 0; i_ < 2; ++i_) {                                   \
                int c_   = (i_ * 4 + w) * 64 + lane;                           \
                int row_ = c_ >> 2;                                            \
                int col_ = ((c_ & 3) ^ (row_ & 3)) * 8;                        \
                gl_lds16(&W[(size_t)(n0 + row_) * DM + (K0) + col_],           \
                         &Bsm[B][(i_ * 4 + w) * 512]);                         \
            }                                                                  \
            _Pragma("unroll")                                                  \
            for (int i_ = 0; i_ < 2; ++i_) {                                   \
                int s_   = tid + i_ * 256;                                     \
                int row_ = s_ >> 2;                                            \
                int col_ = ((s_ & 3) ^ (row_ & 3)) * 8;                        \
                float4 x_ = *(const float4*)&A[(size_t)(m0 + row_) * DM + (K0) + col_];     \
                float4 y_ = *(const float4*)&A[(size_t)(m0 + row_) * DM + (K0) + col_ + 4]; \
                u16x4 lo_, hi_;                                                \
                lo_.x = f2bf(x_.x); lo_.y = f2bf(x_.y);                        \
                lo_.z = f2bf(x_.z); lo_.w = f2bf(x_.w);                        \
                hi_.x = f2bf(y_.x); hi_.y = f2bf(y_.y);                        \
                hi_.z = f2bf(y_.z); hi_.w = f2bf(y_.w);                        \
                *(u16x4*)&Asm[B][s_ * 8]     = lo_;                            \
                *(u16x4*)&Asm[B][s_ * 8 + 4] = hi_;                            \
            }                                                                  \
        } while (0)

    GSTAGE(0, 0);

    for (int kk = 0; kk < DM / 32; ++kk) {
        __syncthreads();                       // publishes buf[kk&1]
        if (kk + 1 < DM / 32) GSTAGE((kk + 1) * 32, (kk + 1) & 1);

        const u16* Ab = Asm[kk & 1];
        const u16* Bb = Bsm[kk & 1];
        bf16x8 af[4], bfr[4];
        #pragma unroll
        for (int mi = 0; mi < 4; ++mi) {
            int r = wr * 64 + mi * 16 + l16;
            af[mi] = *(const bf16x8*)((const char*)Ab + (size_t)r * 64
                                      + (((lg ^ r) & 3) << 4));
        }
        #pragma unroll
        for (int ni = 0; ni < 4; ++ni) {
            int r = wc * 64 + ni * 16 + l16;
            bfr[ni] = *(const bf16x8*)((const char*)Bb + (size_t)r * 64
                                       + (((lg ^ r) & 3) << 4));
        }

        #pragma unroll
        for (int mi = 0; mi < 4; ++mi)
            #pragma unroll
            for (int ni = 0; ni < 4; ++ni)
                acc[mi][ni] = __builtin_amdgcn_mfma_f32_16x16x32_bf16(
                    af[mi], bfr[ni], acc[mi][ni], 0, 0, 0);
    }
    #undef GSTAGE

    #pragma unroll
    for (int mi = 0; mi < 4; ++mi)
        #pragma unroll
        for (int ni = 0; ni < 4; ++ni) {
            int n = n0 + wc * 64 + ni * 16 + l16;
            float bv = bias[n];
            if (op == 2) {
                int hh = n >> 6, dd = n & 63;
                int mb = m0 + wr * 64 + mi * 16 + lg * 4;
                int bI = mb >> 12;
                int kv = mb & (SQ - 1);
                int kvs = (kv & ~12) | ((kv & 4) << 1) | ((kv & 8) >> 1);
                u16x4 pk;
                #pragma unroll
                for (int r = 0; r < 4; ++r)
                    pk[r] = f2bf(acc[mi][ni][r] + bv);
                *(u16x4*)&vto[(((size_t)bI * NH + hh) * DK + dd) * SQ + kvs] = pk;
            } else {
                u16* out = op ? ko : qo;
                #pragma unroll
                for (int r = 0; r < 4; ++r) {
                    int m = m0 + wr * 64 + mi * 16 + lg * 4 + r;
                    out[(size_t)m * DM + n] = f2bf((acc[mi][ni][r] + bv) * oscale);
                }
            }
        }
}

// ---------------------------------------------------------------------------
// Final projection GEMM, 64x128 tile, 768 blocks (verified r16).
// ---------------------------------------------------------------------------
__global__ __launch_bounds__(256) void gemm_out(
    const u16* __restrict__ A, const u16* __restrict__ W,
    const float* __restrict__ bias, float* __restrict__ C)
{
    __shared__ __align__(16) u16 Asm[2][64 * 32];
    __shared__ __align__(16) u16 Bsm[2][128 * 32];

    const int tid  = threadIdx.x;
    const int lane = tid & 63;
    const int w    = tid >> 6;
    const int wr   = w >> 1, wc = w & 1;
    const int l16  = lane & 15, lg = lane >> 4;

    const int ntiles = DM / 128;                // 6
    const int mt = blockIdx.x / ntiles;
    const int nt = blockIdx.x % ntiles;
    const int m0 = mt * 64, n0 = nt * 128;

    f32x4 acc[2][4];
    #pragma unroll
    for (int mi = 0; mi < 2; ++mi)
        #pragma unroll
        for (int ni = 0; ni < 4; ++ni)
            #pragma unroll
            for (int r = 0; r < 4; ++r) acc[mi][ni][r] = 0.f;

    #define OSTAGE(K0, B)                                                      \
        do {                                                                   \
            _Pragma("unroll")                                                  \
            for (int i_ = 0; i_ < 2; ++i_) {                                   \
                int c_   = (i_ * 4 + w) * 64 + lane;                           \
                int row_ = c_ >> 2;                                            \
                int col_ = ((c_ & 3) ^ (row_ & 3)) * 8;                        \
                gl_lds16(&W[(size_t)(n0 + row_) * DM + (K0) + col_],           \
                         &Bsm[B][(i_ * 4 + w) * 512]);                         \
            }                                                                  \
            {                                                                  \
                int c_   = w * 64 + lane;                                      \
                int row_ = c_ >> 2;                                            \
                int col_ = ((c_ & 3) ^ (row_ & 3)) * 8;                        \
                gl_lds16(&A[(size_t)(m0 + row_) * DM + (K0) + col_],           \
                         &Asm[B][w * 512]);                                    \
            }                                                                  \
        } while (0)

    OSTAGE(0, 0);

    for (int kk = 0; kk < DM / 32; ++kk) {
        __syncthreads();
        if (kk + 1 < DM / 32) OSTAGE((kk + 1) * 32, (kk + 1) & 1);

        const u16* Ab = Asm[kk & 1];
        const u16* Bb = Bsm[kk & 1];
        bf16x8 af[2], bfr[4];
        #pragma unroll
        for (int mi = 0; mi < 2; ++mi) {
            int r = wr * 32 + mi * 16 + l16;
            af[mi] = *(const bf16x8*)((const char*)Ab + (size_t)r * 64
                                      + (((lg ^ r) & 3) << 4));
        }
        #pragma unroll
        for (int ni = 0; ni < 4; ++ni) {
            int r = wc * 64 + ni * 16 + l16;
            bfr[ni] = *(const bf16x8*)((const char*)Bb + (size_t)r * 64
                                       + (((lg ^ r) & 3) << 4));
        }

        #pragma unroll
        for (int mi = 0; mi < 2; ++mi)
            #pragma unroll
            for (int ni = 0; ni < 4; ++ni)
                acc[mi][ni] = __builtin_amdgcn_mfma_f32_16x16x32_bf16(
                    af[mi], bfr[ni], acc[mi][ni], 0, 0, 0);
    }
    #undef OSTAGE

    #pragma unroll
    for (int mi = 0; mi < 2; ++mi)
        #pragma unroll
        for (int ni = 0; ni < 4; ++ni) {
            int n = n0 + wc * 64 + ni * 16 + l16;
            float bv = bias[n];
            #pragma unroll
            for (int r = 0; r < 4; ++r) {
                int m = m0 + wr * 32 + mi * 16 + lg * 4 + r;
                C[(size_t)m * DM + n] = acc[mi][ni][r] + bv;
            }
        }
}

// ---------------------------------------------------------------------------
// Flash attention (verified r16/r20): 8 waves, in-block KV-split, 2-phase
// dbuf (2x32KB), XCD swizzle, p=2^s, sigma-permuted V^T (no P-exchange),
// cross-wave merge in LDS.
// ---------------------------------------------------------------------------
__global__ __launch_bounds__(512) void flash_attn_db(
    const u16* __restrict__ Qm, const u16* __restrict__ Km,
    const u16* __restrict__ VT, u16* __restrict__ Om)
{
    __shared__ __align__(16) char ldsbuf[65536];   // 2 x (K0|V0|K1|V1 32KB)

    const int tid  = threadIdx.x;
    const int lane = tid & 63;
    const int w    = tid >> 6;          // 0..7
    const int qg   = w & 3;
    const int half = w >> 2;
    const int kvL  = lane & 31;
    const int hi   = lane >> 5;

    const int bid = blockIdx.x;                  // 0..767
    const int grp = bid >> 3;                    // 0..95
    const int bh  = (bid & 7) * 3 + (grp >> 5);  // 0..23 (bijective)
    const int qt  = grp & 31;                    // 0..31
    const int b   = bh / NH, h = bh % NH;
    const size_t baseQ  = (size_t)b * SQ * DM + (size_t)h * DK;
    const size_t baseVT = (size_t)bh * DK * SQ;

    const int q = qt * 128 + qg * 32 + kvL;

    bf16x8 qf[4];
    #pragma unroll
    for (int j = 0; j < 4; ++j)
        qf[j] = *(const bf16x8*)&Qm[baseQ + (size_t)q * DM + j * 16 + hi * 8];

    int off[4];
    #pragma unroll
    for (int j = 0; j < 4; ++j)
        off[j] = kvL * 128 + (((2 * j + hi) ^ (kvL & 7)) << 4);

    int srow[2], schk[2];
    #pragma unroll
    for (int i = 0; i < 2; ++i) {
        int r = (qg * 2 + i) * 8 + (lane >> 3);
        srow[i] = r;
        schk[i] = (((lane & 7) ^ (r & 7)) << 3);
    }

    f32x16 accO[2];
    #pragma unroll
    for (int e = 0; e < 16; ++e) { accO[0][e] = 0.f; accO[1][e] = 0.f; }
    float lrun = 0.f;

    #define STAGE(T, B)                                                        \
        do {                                                                   \
            int kv0_ = (T) * 128 + half * 64;                                  \
            u16* KL_ = (u16*)(ldsbuf + (B) * 32768 + half * 16384);            \
            u16* VL_ = (u16*)(ldsbuf + (B) * 32768 + half * 16384 + 8192);     \
            _Pragma("unroll")                                                  \
            for (int i_ = 0; i_ < 2; ++i_) {                                   \
                gl_lds16(&Km[baseQ + (size_t)(kv0_ + srow[i_]) * DM + schk[i_]], \
                         KL_ + (qg * 2 + i_) * 512);                           \
                gl_lds16(&VT[baseVT + (size_t)srow[i_] * SQ + kv0_ + schk[i_]], \
                         VL_ + (qg * 2 + i_) * 512);                           \
            }                                                                  \
        } while (0)

    STAGE(0, 0);

    for (int t = 0; t < SQ / 128; ++t) {
        __syncthreads();                // drains own DMA; publishes buf[t&1]
        if (t + 1 < SQ / 128) STAGE(t + 1, (t + 1) & 1);

        const char* KB = ldsbuf + (t & 1) * 32768 + half * 16384;
        const char* VB = KB + 8192;

        // S^T = K . Q (log2 domain)
        f32x16 s0, s1;
        #pragma unroll
        for (int e = 0; e < 16; ++e) { s0[e] = 0.f; s1[e] = 0.f; }
        __builtin_amdgcn_s_setprio(1);
        #pragma unroll
        for (int j = 0; j < 4; ++j) {
            bf16x8 kf0 = *(const bf16x8*)(KB + off[j]);
            bf16x8 kf1 = *(const bf16x8*)(KB + 4096 + off[j]);
            s0 = __builtin_amdgcn_mfma_f32_32x32x16_bf16(kf0, qf[j], s0, 0, 0, 0);
            s1 = __builtin_amdgcn_mfma_f32_32x32x16_bf16(kf1, qf[j], s1, 0, 0, 0);
        }
        __builtin_amdgcn_s_setprio(0);

        // p = 2^s; per-lane partial row sum (cross-half combine deferred)
        u32 pb[16];
        float rs0 = 0.f, rs1 = 0.f;
        #pragma unroll
        for (int wd = 0; wd < 8; ++wd) {
            float a0 = __builtin_amdgcn_exp2f(s0[2 * wd]);
            float a1 = __builtin_amdgcn_exp2f(s0[2 * wd + 1]);
            float b0 = __builtin_amdgcn_exp2f(s1[2 * wd]);
            float b1 = __builtin_amdgcn_exp2f(s1[2 * wd + 1]);
            rs0 += a0 + a1;
            rs1 += b0 + b1;
            pb[wd]     = pack_trunc(a0, a1);
            pb[8 + wd] = pack_trunc(b0, b1);
        }
        lrun += rs0 + rs1;

        // PV: each lane's own pb words ARE the B-fragment (V^T pre-permuted)
        __builtin_amdgcn_s_setprio(1);
        #pragma unroll
        for (int m = 0; m < 4; ++m) {
            int sb = 4 * m;
            u32x4 wds;
            wds[0] = pb[sb + 0];
            wds[1] = pb[sb + 1];
            wds[2] = pb[sb + 2];
            wds[3] = pb[sb + 3];
            bf16x8 Bp = __builtin_bit_cast(bf16x8, wds);
            bf16x8 v0 = *(const bf16x8*)(VB + off[m]);
            bf16x8 v1 = *(const bf16x8*)(VB + 4096 + off[m]);
            accO[0] = __builtin_amdgcn_mfma_f32_32x32x16_bf16(v0, Bp, accO[0], 0, 0, 0);
            accO[1] = __builtin_amdgcn_mfma_f32_32x32x16_bf16(v1, Bp, accO[1], 0, 0, 0);
        }
        __builtin_amdgcn_s_setprio(0);
    }
    #undef STAGE

    __syncthreads();                    // all compute done before merge overlay

    lrun = lrun + __shfl_xor(lrun, 32);

    // ---- cross-wave (kv-split) merge ----
    float* mo = (float*)ldsbuf;                    // [qg][q=32][68] f32
    float* ml = (float*)(ldsbuf + 34816);          // [qg*32+q] f32
    const int rowi = (qg * 32 + kvL);

    if (half == 1) {
        float* row = mo + rowi * 68;
        #pragma unroll
        for (int c = 0; c < 2; ++c)
            #pragma unroll
            for (int e = 0; e < 16; ++e)
                row[(e >> 2) * 8 + (e & 3) + hi * 4 + c * 32] = accO[c][e];
        if (hi == 0) ml[rowi] = lrun;
    }
    __syncthreads();
    if (half == 0) {
        float* row = mo + rowi * 68;
        float inv = 1.f / (lrun + ml[rowi]);
        #pragma unroll
        for (int c = 0; c < 2; ++c)
            #pragma unroll
            for (int t4 = 0; t4 < 4; ++t4) {
                int d0 = t4 * 8 + hi * 4 + c * 32;
                u16x4 pk;
                #pragma unroll
                for (int u = 0; u < 4; ++u) {
                    float val = (accO[c][t4 * 4 + u] + row[d0 + u]) * inv;
                    pk[u] = f2bf(val);
                }
                *(u16x4*)&Om[baseQ + (size_t)q * DM + d0] = pk;
            }
    }
}

// ---------------------------------------------------------------------------
extern "C" void kernel_launch(void* const* d_in, const int* in_sizes, int n_in,
                              void* d_out, int out_size, void* d_ws, size_t ws_size,
                              hipStream_t stream)
{
    const float* Q  = (const float*)d_in[0];
    const float* K  = (const float*)d_in[1];
    const float* V  = (const float*)d_in[2];
    const float* Wq = (const float*)d_in[3];
    const float* bq = (const float*)d_in[4];
    const float* Wk = (const float*)d_in[5];
    const float* bk = (const float*)d_in[6];
    const float* Wv = (const float*)d_in[7];
    const float* bv = (const float*)d_in[8];
    const float* Wo = (const float*)d_in[9];
    const float* bo = (const float*)d_in[10];
    (void)in_sizes; (void)n_in; (void)out_size; (void)ws_size;

    const size_t E  = (size_t)BB * SQ * DM;      // 6291456
    const size_t WE = (size_t)DM * DM;           // 589824
    u16* qws  = (u16*)d_ws;
    u16* kws  = qws + E;
    u16* vtws = kws + E;
    u16* aws  = vtws + E;
    u16* wqb  = aws + E;
    u16* wkb  = wqb + WE;
    u16* wvb  = wkb + WE;
    u16* wob  = wvb + WE;

    const float qscale = 0.125f * 1.4426950408889634f;   // 1/sqrt(64) * log2(e)

    hipLaunchKernelGGL(cvt_w, dim3(WE / 2048, 4), dim3(256), 0, stream,
                       Wq, Wk, Wv, Wo, wqb, wkb, wvb, wob);

    dim3 gq((BB * SQ / BM) * (DM / BN), 3);      // (384, 3)
    hipLaunchKernelGGL(gemm_qkv, gq, dim3(256), 0, stream,
                       Q, K, V, wqb, wkb, wvb, bq, bk, bv,
                       qws, kws, vtws, qscale);

    dim3 ga(768);                                // swizzled 1D grid
    hipLaunchKernelGGL(flash_attn_db, ga, dim3(512), 0, stream, qws, kws, vtws, aws);

    dim3 gg((BB * SQ / 64) * (DM / 128));        // 128*6 = 768
    hipLaunchKernelGGL(gemm_out, gg, dim3(256), 0, stream, aws, wob, bo, (float*)d_out);
}